// Round 7
// baseline (132.424 us; speedup 1.0000x reference)
//
#include <hip/hip_runtime.h>

// GCN, algebraically collapsed + two-sided 256-node bucket partition.
//   y[n]  = dinv[n]*x[n]   (fp16x8, 16B)
//   a[d]  = dinv[d]*(sum_{s->d} y[s] + y[d]);  h1[d] = relu(a[d]@W1 + b1)
//   sdeg[s] = sum_{d: s->d} dinv[d];  c[d] = dinv[d]*sdeg[d] + dinv[d]^2
//   v = sum_d c[d]*h1[d];  g = (1/N)*v@W2 + b2
//   out = concat(g, relu(state@Wm+bm)) @ Wc + bc
// R23 = exact R19 (128.1us, best) + ONE change: k_sacc epilogue vv[64]+
// 64-wide butterfly replaced by 8x8 chunked GEMV+xor-tree reduce. Motive:
// k_sacc counters show VGPR_Count=48 while vv[64]+a[8] has >=70 values
// simultaneously live at the butterfly's first level => compiler spills vv
// to AGPR or scratch. Chunked form caps live floats at ~30 (spill-free by
// construction); same fp32 math reassociated (bf16-granularity compare).
// k_part/k_prep/k_final byte-identical to R19 (PCH=6144 is a measured local
// optimum: 3072 and 8192 both +2.4).
// Falsified on this structure: R13 balanced strips (+1.7), R14 value-carrying
// S-fold (+7.5), R15 cooperative prep+sacc fusion (+56), R17 global-atomic
// sdeg scatter (+54: memory-side fp32 atomics ~32ns each, 47MB HBM RMW),
// R18 fenced finale fusion (+7 k_sacc: per-block L2 writeback), R20 k_part
// PCH-halving + wave-scan (+2.4), R21 fence-free finale fusion (WRONG:
// cross-XCD visibility needs device-scope fences; G16), R22 PCH 8192 (+2.4).

#define NPB   256      // nodes per bucket
#define CAP   4096     // edge capacity per bucket (mean 3200, +15.8 sigma)
#define MAXB  512      // max buckets (N <= 131072)
#define PCH   6144     // edges per partition block
#define PTH   512      // partition block threads
#define PK    (PCH/PTH) // 12 edges per thread
#define SPT   512      // widened k_prep/k_sacc threads (R19)

typedef unsigned uv4 __attribute__((ext_vector_type(4)));
typedef _Float16 half8 __attribute__((ext_vector_type(8)));

// Block-level radix scatter, ONE side per block (blockIdx.y: 0=dst, 1=src).
// Payload u32: low 17 bits = other-endpoint id, bits [24:17] = own low-8.
__launch_bounds__(PTH)
__global__ void k_part(const int* __restrict__ src, const int* __restrict__ dst,
                       int E,
                       unsigned* __restrict__ curD, unsigned* __restrict__ curS,
                       unsigned* __restrict__ bufD, unsigned* __restrict__ bufS) {
    __shared__ unsigned       stage[PCH];   // 24 KB
    __shared__ unsigned short bkt[PCH];     // 12 KB
    __shared__ unsigned lc[MAXB], lofs[MAXB], gb[MAXB], sc[MAXB]; // 8 KB
    int t = threadIdx.x;
    int side = blockIdx.y;
    int base = blockIdx.x * PCH;
    int cnt = min(PCH, E - base);

    unsigned ss[PK], dd[PK];
#pragma unroll
    for (int k = 0; k < PK; ++k) {
        int e = base + k * PTH + t;
        if (e < E) { ss[k] = (unsigned)src[e]; dd[k] = (unsigned)dst[e]; }
        else ss[k] = 0xffffffffu;
    }

    lc[t] = 0;                       // PTH == MAXB
    __syncthreads();

    unsigned br[PK];
#pragma unroll
    for (int k = 0; k < PK; ++k) {
        if (ss[k] == 0xffffffffu) { br[k] = 0xffffffffu; continue; }
        unsigned key = side ? ss[k] : dd[k];
        unsigned b = key >> 8;
        unsigned r = atomicAdd(&lc[b], 1u);
        br[k] = (b << 16) | r;
    }
    __syncthreads();

    // exclusive scan of lc[0..MAXB), 1/thread (Hillis-Steele)
    unsigned v = lc[t];
    sc[t] = v;
    __syncthreads();
    for (int o = 1; o < MAXB; o <<= 1) {
        unsigned add = (t >= o) ? sc[t - o] : 0u;
        __syncthreads();
        sc[t] += add;
        __syncthreads();
    }
    lofs[t] = sc[t] - v;
    gb[t] = v ? atomicAdd(side ? &curS[t] : &curD[t], v) : 0u;
    __syncthreads();

    // stage bucket-ordered
#pragma unroll
    for (int k = 0; k < PK; ++k) {
        if (br[k] == 0xffffffffu) continue;
        unsigned b = br[k] >> 16, r = br[k] & 0xffffu;
        unsigned pos = lofs[b] + r;
        stage[pos] = side ? (dd[k] | ((ss[k] & 255u) << 17))
                          : (ss[k] | ((dd[k] & 255u) << 17));
        bkt[pos] = (unsigned short)b;
    }
    __syncthreads();

    // contiguous-run writeout (runs avg ~15.7 words)
    unsigned* obuf = side ? bufS : bufD;
    for (int i = t; i < cnt; i += PTH) {
        unsigned b = bkt[i];
        obuf[(size_t)b * CAP + gb[b] + ((unsigned)i - lofs[b])] = stage[i];
    }
}

// Per dst-bucket: hist (1 LDS atomic/edge) -> counting sort persisted to
// sortD + eoffsG (coalesced); dinv + yh = fp16(dinv*x). NO global atomics.
// R19: 512 threads (2 uv4 each, 8 waves/block for latency hiding); scans
// and node math masked to t<256.
__launch_bounds__(SPT)
__global__ void k_prep(const unsigned* __restrict__ bufD, const unsigned* __restrict__ cntD,
                       const float* __restrict__ x, int N,
                       float* __restrict__ dinv, half8* __restrict__ yh,
                       unsigned* __restrict__ sortD, unsigned* __restrict__ eoffsG) {
    __shared__ unsigned sorted[CAP];    // 16 KB
    __shared__ unsigned degl[NPB], scs[NPB], eoffs[NPB];
    int t = threadIdx.x, b = blockIdx.x;
    if (t < NPB) degl[t] = 0u;
    __syncthreads();

    unsigned cnt = cntD[b];
    const uv4* eb = (const uv4*)(bufD + (size_t)b * CAP);
    uv4 w[2];
    unsigned short rk[8];
#pragma unroll
    for (int r = 0; r < 2; ++r) {
        unsigned base = ((unsigned)t + (unsigned)r * SPT) * 4u;
        if (base < cnt) {
            w[r] = eb[t + r * SPT];
            unsigned nv = min(cnt - base, 4u);
#pragma unroll
            for (unsigned k = 0; k < 4; ++k)
                if (k < nv)
                    rk[r * 4 + k] = (unsigned short)atomicAdd(&degl[w[r][k] >> 17], 1u);
        }
    }
    __syncthreads();

    // exclusive scan of degl (256 bins; t<256 active, all threads at barriers)
    unsigned hv = 0u;
    if (t < NPB) { hv = degl[t]; scs[t] = hv; }
    __syncthreads();
    for (int o = 1; o < NPB; o <<= 1) {
        unsigned add = (t < NPB && t >= o) ? scs[t - o] : 0u;
        __syncthreads();
        if (t < NPB) scs[t] += add;
        __syncthreads();
    }
    if (t < NPB) eoffs[t] = scs[t] - hv;
    __syncthreads();

    // place into sorted order (plain LDS writes)
#pragma unroll
    for (int r = 0; r < 2; ++r) {
        unsigned base = ((unsigned)t + (unsigned)r * SPT) * 4u;
        if (base < cnt) {
            unsigned nv = min(cnt - base, 4u);
#pragma unroll
            for (unsigned k = 0; k < 4; ++k)
                if (k < nv)
                    sorted[eoffs[w[r][k] >> 17] + rk[r * 4 + k]] = w[r][k];
        }
    }
    __syncthreads();

    // persist sort (coalesced; trailing garbage beyond cnt never read)
    uv4* so = (uv4*)(sortD + (size_t)b * CAP);
    const uv4* slv = (const uv4*)sorted;
#pragma unroll
    for (int r = 0; r < 2; ++r) so[t + r * SPT] = slv[t + r * SPT];

    if (t < NPB) {
        eoffsG[(size_t)b * NPB + t] = eoffs[t];
        int n = b * NPB + t;
        if (n < N) {
            float di = rsqrtf((float)(degl[t] + 1u));
            dinv[n] = di;
            float4 u0 = ((const float4*)(x + (size_t)n * 8))[0];
            float4 u1 = ((const float4*)(x + (size_t)n * 8))[1];
            half8 h;
            h[0] = (_Float16)(di * u0.x); h[1] = (_Float16)(di * u0.y);
            h[2] = (_Float16)(di * u0.z); h[3] = (_Float16)(di * u0.w);
            h[4] = (_Float16)(di * u1.x); h[5] = (_Float16)(di * u1.y);
            h[6] = (_Float16)(di * u1.z); h[7] = (_Float16)(di * u1.w);
            yh[n] = h;
        }
    }
}

// Per bucket b: sdeg via LDS float atomics over bufS (1/edge); D side reads
// each node's sorted segment DIRECTLY from global (contiguous,
// single-consumer), segmented register reduce, fused node math, chunked
// GEMV + xor-tree reduce (R23: spill-free, max ~30 live floats), fold into
// vsum[64].
// R19: 512 threads. S-side edges split 2 uv4/thread; D-side node m's segment
// split between thread pair (m, m+256): lower [0,deg/2), upper [deg/2,deg),
// combined via LDS.
__launch_bounds__(SPT)
__global__ void k_sacc(const unsigned* __restrict__ sortD, const unsigned* __restrict__ cntD,
                       const unsigned* __restrict__ eoffsG,
                       const unsigned* __restrict__ bufS, const unsigned* __restrict__ cntS,
                       const half8* __restrict__ yh, const float* __restrict__ dinv,
                       const float* __restrict__ W1, const float* __restrict__ b1,
                       float* __restrict__ vsum, int N) {
    __shared__ unsigned eo[NPB + 1];
    __shared__ float sl[NPB];
    __shared__ float W1s[512];
    __shared__ float b1s[64];
    __shared__ float red[4][64];
    __shared__ float acc2[NPB][8];      // upper-half partial sums (8 KB)
    int t = threadIdx.x, b = blockIdx.x;
    W1s[t] = W1[t];                     // 512 threads, one each
    if (t < 64) b1s[t] = b1[t];
    if (t < NPB) {
        sl[t] = 0.f;
        eo[t] = eoffsG[(size_t)b * NPB + t];
    }
    if (t == 0) eo[NPB] = cntD[b];
    __syncthreads();

    // S side: sdeg (LDS float atomic 1/edge, batched-4 dinv gathers)
    {
        unsigned cnt = cntS[b];
        const uv4* eb = (const uv4*)(bufS + (size_t)b * CAP);
#pragma unroll
        for (int r = 0; r < 2; ++r) {
            unsigned base = ((unsigned)t + (unsigned)r * SPT) * 4u;
            if (base < cnt) {
                uv4 w = eb[t + r * SPT];
                unsigned nv = min(cnt - base, 4u);
                float dv[4];
#pragma unroll
                for (unsigned k = 0; k < 4; ++k)
                    dv[k] = (k < nv) ? dinv[w[k] & 0x1ffffu] : 0.f;
#pragma unroll
                for (unsigned k = 0; k < 4; ++k)
                    if (k < nv) atomicAdd(&sl[w[k] >> 17], dv[k]);
            }
        }
    }

    // D side: node m's sorted segment split between thread pair (m, m+256)
    int m = t & (NPB - 1);
    int hh = t >> 8;                    // 0 = lower half, 1 = upper half
    unsigned e0 = eo[m], deg = eo[m + 1] - e0;
    unsigned beg = hh ? (deg >> 1) : 0u;
    unsigned end = hh ? deg : (deg >> 1);
    const unsigned* seg = sortD + (size_t)b * CAP + e0;
    float a[8] = {0.f, 0.f, 0.f, 0.f, 0.f, 0.f, 0.f, 0.f};
    unsigned i = beg;
    for (; i + 4 <= end; i += 4) {
        unsigned s0 = seg[i]     & 0x1ffffu;
        unsigned s1 = seg[i + 1] & 0x1ffffu;
        unsigned s2 = seg[i + 2] & 0x1ffffu;
        unsigned s3 = seg[i + 3] & 0x1ffffu;
        half8 g0 = yh[s0], g1 = yh[s1], g2 = yh[s2], g3 = yh[s3];
#pragma unroll
        for (int j = 0; j < 8; ++j)
            a[j] += ((float)g0[j] + (float)g1[j]) + ((float)g2[j] + (float)g3[j]);
    }
    for (; i < end; ++i) {
        half8 g = yh[seg[i] & 0x1ffffu];
#pragma unroll
        for (int j = 0; j < 8; ++j) a[j] += (float)g[j];
    }

    if (hh) {
#pragma unroll
        for (int j = 0; j < 8; ++j) acc2[m][j] = a[j];
    }
    __syncthreads();   // acc2 ready AND sl complete before node math

    if (t < NPB) {
#pragma unroll
        for (int j = 0; j < 8; ++j) a[j] += acc2[m][j];

        int n = b * NPB + m;
        float c = 0.f;
        if (n < N) {
            float di = rsqrtf((float)(deg + 1u));
            half8 hs = yh[n];
#pragma unroll
            for (int j = 0; j < 8; ++j) a[j] = di * (a[j] + (float)hs[j]);
            c = fmaf(di, sl[m], di * di);
        } else {
#pragma unroll
            for (int j = 0; j < 8; ++j) a[j] = 0.f;
        }

        // R23: chunked GEMV + xor-tree reduce. Per chunk of 8 outputs:
        // compute h (8 live regs), tree-sum each across the full wave
        // (waves 0-3 fully active here), owner lane keeps its component.
        // Replaces vv[64]+butterfly (>=70 live floats vs VGPR_Count=48 =>
        // compiler spill). Same fp32 sums, reassociated.
        int lane = t & 63;
        float keep = 0.f;
#pragma unroll
        for (int kc = 0; kc < 8; ++kc) {
            float w[8];
#pragma unroll
            for (int i2 = 0; i2 < 8; ++i2) {
                int k = kc * 8 + i2;
                float h = b1s[k];
#pragma unroll
                for (int j = 0; j < 8; ++j) h = fmaf(a[j], W1s[j * 64 + k], h);
                w[i2] = c * fmaxf(h, 0.f);
            }
#pragma unroll
            for (int i2 = 0; i2 < 8; ++i2) {
#pragma unroll
                for (int e = 32; e >= 1; e >>= 1)
                    w[i2] += __shfl_xor(w[i2], e);
            }
            if ((lane >> 3) == kc) keep = w[lane & 7];
        }
        red[t >> 6][lane] = keep;
    }
    __syncthreads();
    if (t < 64)
        unsafeAtomicAdd(&vsum[t], red[0][t] + red[1][t] + red[2][t] + red[3][t]);
}

// Single block, 64 threads: g = (1/N)*vsum@W2+b2, s = relu(state@Wm+bm),
// out = [g,s]@Wc+bc.
__global__ void k_final(const float* __restrict__ vsum,
                        const float* __restrict__ W2, const float* __restrict__ b2,
                        const float* __restrict__ state, const float* __restrict__ Wm,
                        const float* __restrict__ bm, const float* __restrict__ Wc,
                        const float* __restrict__ bc, float* __restrict__ out,
                        float inv_n) {
    __shared__ float v[64];
    __shared__ float gs[128];
    int k = threadIdx.x;   // blockDim = 64

    v[k] = vsum[k];
    __syncthreads();

    float g = 0.f;
    for (int j = 0; j < 64; ++j) g = fmaf(v[j], W2[j * 64 + k], g);
    g = fmaf(g, inv_n, b2[k]);

    float s = bm[k];
    for (int j = 0; j < 8; ++j) s = fmaf(state[j], Wm[j * 64 + k], s);
    s = fmaxf(s, 0.f);

    gs[k] = g;
    gs[64 + k] = s;
    __syncthreads();

    if (k < 2) {
        float o = bc[k];
        for (int j = 0; j < 128; ++j) o = fmaf(gs[j], Wc[j * 2 + k], o);
        out[k] = o;
    }
}

extern "C" void kernel_launch(void* const* d_in, const int* in_sizes, int n_in,
                              void* d_out, int out_size, void* d_ws, size_t ws_size,
                              hipStream_t stream) {
    const float* x     = (const float*)d_in[0];
    const float* state = (const float*)d_in[1];
    const float* W1    = (const float*)d_in[2];
    const float* b1    = (const float*)d_in[3];
    const float* W2    = (const float*)d_in[4];
    const float* b2    = (const float*)d_in[5];
    const float* Wm    = (const float*)d_in[6];
    const float* bm    = (const float*)d_in[7];
    const float* Wc    = (const float*)d_in[8];
    const float* bc    = (const float*)d_in[9];
    const int*   ei    = (const int*)d_in[10];

    const int N = in_sizes[0] / 8;
    const int E = in_sizes[10] / 2;
    const int* src = ei;
    const int* dst = ei + E;
    const int nbuck = (N + NPB - 1) / NPB;   // 391 for N=100000

    char* ws = (char*)d_ws;
    size_t off = 0;
    auto alloc = [&](size_t bytes) -> void* {
        void* p = ws + off;
        off += (bytes + 255) & ~(size_t)255;
        return p;
    };
    // Zeroed region: cursors + vsum (~4.4 KB).
    unsigned* curD = (unsigned*)alloc((size_t)MAXB * 4);
    unsigned* curS = (unsigned*)alloc((size_t)MAXB * 4);
    float*    vsum = (float*)   alloc(64 * 4);
    size_t zero_bytes = off;
    // No-init region.
    unsigned* bufD   = (unsigned*)alloc((size_t)nbuck * CAP * 4);
    unsigned* bufS   = (unsigned*)alloc((size_t)nbuck * CAP * 4);
    unsigned* sortD  = (unsigned*)alloc((size_t)nbuck * CAP * 4);
    unsigned* eoffsG = (unsigned*)alloc((size_t)nbuck * NPB * 4);
    float*    dinv   = (float*)   alloc((size_t)N * 4);
    half8*    yh     = (half8*)   alloc((size_t)N * 16);
    (void)ws_size; (void)n_in; (void)out_size;

    hipMemsetAsync(d_ws, 0, zero_bytes, stream);

    dim3 pgrid((E + PCH - 1) / PCH, 2);
    k_part<<<pgrid, PTH, 0, stream>>>(src, dst, E, curD, curS, bufD, bufS);
    k_prep<<<nbuck, SPT, 0, stream>>>(bufD, curD, x, N, dinv, yh, sortD, eoffsG);
    k_sacc<<<nbuck, SPT, 0, stream>>>(sortD, curD, eoffsG, bufS, curS, yh, dinv,
                                      W1, b1, vsum, N);
    k_final<<<1, 64, 0, stream>>>(vsum, W2, b2, state, Wm, bm, Wc, bc,
                                  (float*)d_out, 1.0f / (float)N);
}

// Round 8
// 127.615 us; speedup vs baseline: 1.0377x; 1.0377x over previous
//
#include <hip/hip_runtime.h>

// GCN, algebraically collapsed + two-sided 256-node bucket partition.
//   y[n]  = dinv[n]*x[n]   (fp16x8, 16B)
//   a[d]  = dinv[d]*(sum_{s->d} y[s] + y[d]);  h1[d] = relu(a[d]@W1 + b1)
//   sdeg[s] = sum_{d: s->d} dinv[d];  c[d] = dinv[d]*sdeg[d] + dinv[d]^2
//   v = sum_d c[d]*h1[d];  g = (1/N)*v@W2 + b2
//   out = concat(g, relu(state@Wm+bm)) @ Wc + bc
// R24 = exact revert to R19 (128.1us, best measured, passed) — terminal
// kernel. R19 = R12 + k_prep/k_sacc widened 256->512 threads (8 waves/block;
// D-side segment split across thread pairs). Since R19, every direction
// falsified with mechanism:
//   R17 global-atomic sdeg (+54: memory-side fp32 atomics ~32ns, 47MB RMW)
//   R18 fenced finale fusion (+7 k_sacc: per-block L2 writeback)
//   R20 PCH 3072 + wave-scan (+2.4: writeout run-length dominates path)
//   R21 fence-free finale fusion (WRONG: cross-XCD visibility needs
//       device-scope fences, G16)
//   R22 PCH 8192 (+2.4: PCH 6144 is a genuine local optimum)
//   R23 spill-free chunked epilogue (+4.3: vv[64] spill was AGPR ~free;
//       384 extra shfl_xor are not)
// Counters: all pipes <10% busy, zero bank conflicts, occupancy lever
// captured by R19. Remaining time = distributed latency floor: ~5M
// inherently-scattered ops (2.5M LDS hist-RMW + 2.5M LDS scatter + 2.5M
// scattered global stores + 1.25M random 16B gathers + 1.25M LDS float
// atomics) / 256 CUs at ~25-30ns effective each ~= 125-130us.

#define NPB   256      // nodes per bucket
#define CAP   4096     // edge capacity per bucket (mean 3200, +15.8 sigma)
#define MAXB  512      // max buckets (N <= 131072)
#define PCH   6144     // edges per partition block
#define PTH   512      // partition block threads
#define PK    (PCH/PTH) // 12 edges per thread
#define SPT   512      // widened k_prep/k_sacc threads (R19)

typedef unsigned uv4 __attribute__((ext_vector_type(4)));
typedef _Float16 half8 __attribute__((ext_vector_type(8)));

// Block-level radix scatter, ONE side per block (blockIdx.y: 0=dst, 1=src).
// Payload u32: low 17 bits = other-endpoint id, bits [24:17] = own low-8.
__launch_bounds__(PTH)
__global__ void k_part(const int* __restrict__ src, const int* __restrict__ dst,
                       int E,
                       unsigned* __restrict__ curD, unsigned* __restrict__ curS,
                       unsigned* __restrict__ bufD, unsigned* __restrict__ bufS) {
    __shared__ unsigned       stage[PCH];   // 24 KB
    __shared__ unsigned short bkt[PCH];     // 12 KB
    __shared__ unsigned lc[MAXB], lofs[MAXB], gb[MAXB], sc[MAXB]; // 8 KB
    int t = threadIdx.x;
    int side = blockIdx.y;
    int base = blockIdx.x * PCH;
    int cnt = min(PCH, E - base);

    unsigned ss[PK], dd[PK];
#pragma unroll
    for (int k = 0; k < PK; ++k) {
        int e = base + k * PTH + t;
        if (e < E) { ss[k] = (unsigned)src[e]; dd[k] = (unsigned)dst[e]; }
        else ss[k] = 0xffffffffu;
    }

    lc[t] = 0;                       // PTH == MAXB
    __syncthreads();

    unsigned br[PK];
#pragma unroll
    for (int k = 0; k < PK; ++k) {
        if (ss[k] == 0xffffffffu) { br[k] = 0xffffffffu; continue; }
        unsigned key = side ? ss[k] : dd[k];
        unsigned b = key >> 8;
        unsigned r = atomicAdd(&lc[b], 1u);
        br[k] = (b << 16) | r;
    }
    __syncthreads();

    // exclusive scan of lc[0..MAXB), 1/thread (Hillis-Steele)
    unsigned v = lc[t];
    sc[t] = v;
    __syncthreads();
    for (int o = 1; o < MAXB; o <<= 1) {
        unsigned add = (t >= o) ? sc[t - o] : 0u;
        __syncthreads();
        sc[t] += add;
        __syncthreads();
    }
    lofs[t] = sc[t] - v;
    gb[t] = v ? atomicAdd(side ? &curS[t] : &curD[t], v) : 0u;
    __syncthreads();

    // stage bucket-ordered
#pragma unroll
    for (int k = 0; k < PK; ++k) {
        if (br[k] == 0xffffffffu) continue;
        unsigned b = br[k] >> 16, r = br[k] & 0xffffu;
        unsigned pos = lofs[b] + r;
        stage[pos] = side ? (dd[k] | ((ss[k] & 255u) << 17))
                          : (ss[k] | ((dd[k] & 255u) << 17));
        bkt[pos] = (unsigned short)b;
    }
    __syncthreads();

    // contiguous-run writeout (runs avg ~15.7 words)
    unsigned* obuf = side ? bufS : bufD;
    for (int i = t; i < cnt; i += PTH) {
        unsigned b = bkt[i];
        obuf[(size_t)b * CAP + gb[b] + ((unsigned)i - lofs[b])] = stage[i];
    }
}

// Per dst-bucket: hist (1 LDS atomic/edge) -> counting sort persisted to
// sortD + eoffsG (coalesced); dinv + yh = fp16(dinv*x). NO global atomics.
// R19: 512 threads (2 uv4 each, 8 waves/block for latency hiding); scans
// and node math masked to t<256.
__launch_bounds__(SPT)
__global__ void k_prep(const unsigned* __restrict__ bufD, const unsigned* __restrict__ cntD,
                       const float* __restrict__ x, int N,
                       float* __restrict__ dinv, half8* __restrict__ yh,
                       unsigned* __restrict__ sortD, unsigned* __restrict__ eoffsG) {
    __shared__ unsigned sorted[CAP];    // 16 KB
    __shared__ unsigned degl[NPB], scs[NPB], eoffs[NPB];
    int t = threadIdx.x, b = blockIdx.x;
    if (t < NPB) degl[t] = 0u;
    __syncthreads();

    unsigned cnt = cntD[b];
    const uv4* eb = (const uv4*)(bufD + (size_t)b * CAP);
    uv4 w[2];
    unsigned short rk[8];
#pragma unroll
    for (int r = 0; r < 2; ++r) {
        unsigned base = ((unsigned)t + (unsigned)r * SPT) * 4u;
        if (base < cnt) {
            w[r] = eb[t + r * SPT];
            unsigned nv = min(cnt - base, 4u);
#pragma unroll
            for (unsigned k = 0; k < 4; ++k)
                if (k < nv)
                    rk[r * 4 + k] = (unsigned short)atomicAdd(&degl[w[r][k] >> 17], 1u);
        }
    }
    __syncthreads();

    // exclusive scan of degl (256 bins; t<256 active, all threads at barriers)
    unsigned hv = 0u;
    if (t < NPB) { hv = degl[t]; scs[t] = hv; }
    __syncthreads();
    for (int o = 1; o < NPB; o <<= 1) {
        unsigned add = (t < NPB && t >= o) ? scs[t - o] : 0u;
        __syncthreads();
        if (t < NPB) scs[t] += add;
        __syncthreads();
    }
    if (t < NPB) eoffs[t] = scs[t] - hv;
    __syncthreads();

    // place into sorted order (plain LDS writes)
#pragma unroll
    for (int r = 0; r < 2; ++r) {
        unsigned base = ((unsigned)t + (unsigned)r * SPT) * 4u;
        if (base < cnt) {
            unsigned nv = min(cnt - base, 4u);
#pragma unroll
            for (unsigned k = 0; k < 4; ++k)
                if (k < nv)
                    sorted[eoffs[w[r][k] >> 17] + rk[r * 4 + k]] = w[r][k];
        }
    }
    __syncthreads();

    // persist sort (coalesced; trailing garbage beyond cnt never read)
    uv4* so = (uv4*)(sortD + (size_t)b * CAP);
    const uv4* slv = (const uv4*)sorted;
#pragma unroll
    for (int r = 0; r < 2; ++r) so[t + r * SPT] = slv[t + r * SPT];

    if (t < NPB) {
        eoffsG[(size_t)b * NPB + t] = eoffs[t];
        int n = b * NPB + t;
        if (n < N) {
            float di = rsqrtf((float)(degl[t] + 1u));
            dinv[n] = di;
            float4 u0 = ((const float4*)(x + (size_t)n * 8))[0];
            float4 u1 = ((const float4*)(x + (size_t)n * 8))[1];
            half8 h;
            h[0] = (_Float16)(di * u0.x); h[1] = (_Float16)(di * u0.y);
            h[2] = (_Float16)(di * u0.z); h[3] = (_Float16)(di * u0.w);
            h[4] = (_Float16)(di * u1.x); h[5] = (_Float16)(di * u1.y);
            h[6] = (_Float16)(di * u1.z); h[7] = (_Float16)(di * u1.w);
            yh[n] = h;
        }
    }
}

// Per bucket b: sdeg via LDS float atomics over bufS (1/edge); D side reads
// each node's sorted segment DIRECTLY from global (contiguous,
// single-consumer), segmented register reduce, fused node math, butterfly
// reduce-scatter, fold into vsum[64].
// R19: 512 threads. S-side edges split 2 uv4/thread; D-side node m's segment
// split between thread pair (m, m+256): lower [0,deg/2), upper [deg/2,deg),
// combined via LDS. GEMV + butterfly verbatim on t<256 (full waves 0-3).
__launch_bounds__(SPT)
__global__ void k_sacc(const unsigned* __restrict__ sortD, const unsigned* __restrict__ cntD,
                       const unsigned* __restrict__ eoffsG,
                       const unsigned* __restrict__ bufS, const unsigned* __restrict__ cntS,
                       const half8* __restrict__ yh, const float* __restrict__ dinv,
                       const float* __restrict__ W1, const float* __restrict__ b1,
                       float* __restrict__ vsum, int N) {
    __shared__ unsigned eo[NPB + 1];
    __shared__ float sl[NPB];
    __shared__ float W1s[512];
    __shared__ float b1s[64];
    __shared__ float red[4][64];
    __shared__ float acc2[NPB][8];      // upper-half partial sums (8 KB)
    int t = threadIdx.x, b = blockIdx.x;
    W1s[t] = W1[t];                     // 512 threads, one each
    if (t < 64) b1s[t] = b1[t];
    if (t < NPB) {
        sl[t] = 0.f;
        eo[t] = eoffsG[(size_t)b * NPB + t];
    }
    if (t == 0) eo[NPB] = cntD[b];
    __syncthreads();

    // S side: sdeg (LDS float atomic 1/edge, batched-4 dinv gathers)
    {
        unsigned cnt = cntS[b];
        const uv4* eb = (const uv4*)(bufS + (size_t)b * CAP);
#pragma unroll
        for (int r = 0; r < 2; ++r) {
            unsigned base = ((unsigned)t + (unsigned)r * SPT) * 4u;
            if (base < cnt) {
                uv4 w = eb[t + r * SPT];
                unsigned nv = min(cnt - base, 4u);
                float dv[4];
#pragma unroll
                for (unsigned k = 0; k < 4; ++k)
                    dv[k] = (k < nv) ? dinv[w[k] & 0x1ffffu] : 0.f;
#pragma unroll
                for (unsigned k = 0; k < 4; ++k)
                    if (k < nv) atomicAdd(&sl[w[k] >> 17], dv[k]);
            }
        }
    }

    // D side: node m's sorted segment split between thread pair (m, m+256)
    int m = t & (NPB - 1);
    int hh = t >> 8;                    // 0 = lower half, 1 = upper half
    unsigned e0 = eo[m], deg = eo[m + 1] - e0;
    unsigned beg = hh ? (deg >> 1) : 0u;
    unsigned end = hh ? deg : (deg >> 1);
    const unsigned* seg = sortD + (size_t)b * CAP + e0;
    float a[8] = {0.f, 0.f, 0.f, 0.f, 0.f, 0.f, 0.f, 0.f};
    unsigned i = beg;
    for (; i + 4 <= end; i += 4) {
        unsigned s0 = seg[i]     & 0x1ffffu;
        unsigned s1 = seg[i + 1] & 0x1ffffu;
        unsigned s2 = seg[i + 2] & 0x1ffffu;
        unsigned s3 = seg[i + 3] & 0x1ffffu;
        half8 g0 = yh[s0], g1 = yh[s1], g2 = yh[s2], g3 = yh[s3];
#pragma unroll
        for (int j = 0; j < 8; ++j)
            a[j] += ((float)g0[j] + (float)g1[j]) + ((float)g2[j] + (float)g3[j]);
    }
    for (; i < end; ++i) {
        half8 g = yh[seg[i] & 0x1ffffu];
#pragma unroll
        for (int j = 0; j < 8; ++j) a[j] += (float)g[j];
    }

    if (hh) {
#pragma unroll
        for (int j = 0; j < 8; ++j) acc2[m][j] = a[j];
    }
    __syncthreads();   // acc2 ready AND sl complete before node math

    if (t < NPB) {
#pragma unroll
        for (int j = 0; j < 8; ++j) a[j] += acc2[m][j];

        int n = b * NPB + m;
        float c = 0.f;
        if (n < N) {
            float di = rsqrtf((float)(deg + 1u));
            half8 hs = yh[n];
#pragma unroll
            for (int j = 0; j < 8; ++j) a[j] = di * (a[j] + (float)hs[j]);
            c = fmaf(di, sl[m], di * di);
        } else {
#pragma unroll
            for (int j = 0; j < 8; ++j) a[j] = 0.f;
        }

        float vv[64];
#pragma unroll
        for (int k = 0; k < 64; ++k) {
            float h = b1s[k];
#pragma unroll
            for (int j = 0; j < 8; ++j) h = fmaf(a[j], W1s[j * 64 + k], h);
            vv[k] = c * fmaxf(h, 0.f);
        }

        // Butterfly reduce-scatter (validated R2-R15): lane l ends with
        // wave-sum of component l in vv[0]. Waves 0-3 fully active here.
        // (vv[64] spills to AGPRs — measured free; R23's spill-free
        // rewrite was +4.3us.)
        int lane = t & 63;
#pragma unroll
        for (int half = 32; half >= 1; half >>= 1) {
            bool upper = (lane & half) != 0;
#pragma unroll
            for (int i2 = 0; i2 < 32; ++i2) {
                if (i2 >= half) break;
                float lo = vv[i2];
                float hi = vv[i2 + half];
                float give = upper ? lo : hi;
                float keep = upper ? hi : lo;
                float recv = __shfl_xor(give, half);
                vv[i2] = keep + recv;
            }
        }
        red[t >> 6][lane] = vv[0];
    }
    __syncthreads();
    if (t < 64)
        unsafeAtomicAdd(&vsum[t], red[0][t] + red[1][t] + red[2][t] + red[3][t]);
}

// Single block, 64 threads: g = (1/N)*vsum@W2+b2, s = relu(state@Wm+bm),
// out = [g,s]@Wc+bc.
__global__ void k_final(const float* __restrict__ vsum,
                        const float* __restrict__ W2, const float* __restrict__ b2,
                        const float* __restrict__ state, const float* __restrict__ Wm,
                        const float* __restrict__ bm, const float* __restrict__ Wc,
                        const float* __restrict__ bc, float* __restrict__ out,
                        float inv_n) {
    __shared__ float v[64];
    __shared__ float gs[128];
    int k = threadIdx.x;   // blockDim = 64

    v[k] = vsum[k];
    __syncthreads();

    float g = 0.f;
    for (int j = 0; j < 64; ++j) g = fmaf(v[j], W2[j * 64 + k], g);
    g = fmaf(g, inv_n, b2[k]);

    float s = bm[k];
    for (int j = 0; j < 8; ++j) s = fmaf(state[j], Wm[j * 64 + k], s);
    s = fmaxf(s, 0.f);

    gs[k] = g;
    gs[64 + k] = s;
    __syncthreads();

    if (k < 2) {
        float o = bc[k];
        for (int j = 0; j < 128; ++j) o = fmaf(gs[j], Wc[j * 2 + k], o);
        out[k] = o;
    }
}

extern "C" void kernel_launch(void* const* d_in, const int* in_sizes, int n_in,
                              void* d_out, int out_size, void* d_ws, size_t ws_size,
                              hipStream_t stream) {
    const float* x     = (const float*)d_in[0];
    const float* state = (const float*)d_in[1];
    const float* W1    = (const float*)d_in[2];
    const float* b1    = (const float*)d_in[3];
    const float* W2    = (const float*)d_in[4];
    const float* b2    = (const float*)d_in[5];
    const float* Wm    = (const float*)d_in[6];
    const float* bm    = (const float*)d_in[7];
    const float* Wc    = (const float*)d_in[8];
    const float* bc    = (const float*)d_in[9];
    const int*   ei    = (const int*)d_in[10];

    const int N = in_sizes[0] / 8;
    const int E = in_sizes[10] / 2;
    const int* src = ei;
    const int* dst = ei + E;
    const int nbuck = (N + NPB - 1) / NPB;   // 391 for N=100000

    char* ws = (char*)d_ws;
    size_t off = 0;
    auto alloc = [&](size_t bytes) -> void* {
        void* p = ws + off;
        off += (bytes + 255) & ~(size_t)255;
        return p;
    };
    // Zeroed region: cursors + vsum (~4.4 KB).
    unsigned* curD = (unsigned*)alloc((size_t)MAXB * 4);
    unsigned* curS = (unsigned*)alloc((size_t)MAXB * 4);
    float*    vsum = (float*)   alloc(64 * 4);
    size_t zero_bytes = off;
    // No-init region.
    unsigned* bufD   = (unsigned*)alloc((size_t)nbuck * CAP * 4);
    unsigned* bufS   = (unsigned*)alloc((size_t)nbuck * CAP * 4);
    unsigned* sortD  = (unsigned*)alloc((size_t)nbuck * CAP * 4);
    unsigned* eoffsG = (unsigned*)alloc((size_t)nbuck * NPB * 4);
    float*    dinv   = (float*)   alloc((size_t)N * 4);
    half8*    yh     = (half8*)   alloc((size_t)N * 16);
    (void)ws_size; (void)n_in; (void)out_size;

    hipMemsetAsync(d_ws, 0, zero_bytes, stream);

    dim3 pgrid((E + PCH - 1) / PCH, 2);
    k_part<<<pgrid, PTH, 0, stream>>>(src, dst, E, curD, curS, bufD, bufS);
    k_prep<<<nbuck, SPT, 0, stream>>>(bufD, curD, x, N, dinv, yh, sortD, eoffsG);
    k_sacc<<<nbuck, SPT, 0, stream>>>(sortD, curD, eoffsG, bufS, curS, yh, dinv,
                                      W1, b1, vsum, N);
    k_final<<<1, 64, 0, stream>>>(vsum, W2, b2, state, Wm, bm, Wc, bc,
                                  (float*)d_out, 1.0f / (float)N);
}